// Round 4
// baseline (291.879 us; speedup 1.0000x reference)
//
#include <hip/hip_runtime.h>
#include <hip/hip_bf16.h>

#define S_LEN   2048
#define HID     1024
#define NH      16
#define HD      64
#define WIN     512
#define NW      4
#define NG      64
#define GSTRIDE 32
#define SCALE   0.125f               // 64^-0.5
#define SCALE_LOG2E 0.180336880f    // 0.125 * log2(e)

#if __has_builtin(__builtin_amdgcn_exp2f)
#define EXP2F(x) __builtin_amdgcn_exp2f(x)
#else
#define EXP2F(x) __expf((x) * 0.6931471805599453f)
#endif

typedef __bf16 bf16x2 __attribute__((ext_vector_type(2)));
typedef __bf16 bf16x8 __attribute__((ext_vector_type(8)));
typedef float  f32x4  __attribute__((ext_vector_type(4)));
typedef unsigned short ushort_t;

// ---------------- fp32 -> bf16 helpers ----------------
__device__ __forceinline__ ushort_t f32_to_bf16_rne(float f) {
    unsigned int u = __float_as_uint(f);
    u = u + 0x7FFFu + ((u >> 16) & 1u);
    return (ushort_t)(u >> 16);
}
__device__ __forceinline__ float bf16_to_f32(ushort_t h) {
    return __uint_as_float(((unsigned int)h) << 16);
}
// packed conversion: gfx950 HW v_cvt_pk_bf16_f32 (RNE), 2 values/instruction
#if __has_builtin(__builtin_amdgcn_cvt_pk_bf16_f32)
__device__ __forceinline__ unsigned int pk_bf16(float a, float b) {
    bf16x2 t = __builtin_amdgcn_cvt_pk_bf16_f32(a, b);
    return __builtin_bit_cast(unsigned int, t);
}
#else
__device__ __forceinline__ unsigned int pk_bf16(float a, float b) {
    return (unsigned int)f32_to_bf16_rne(a) | ((unsigned int)f32_to_bf16_rne(b) << 16);
}
#endif

// ---------------- batched cast: 5 tensors fp32 -> bf16 in one launch ----------------
struct CastJobs {
    const float* in[5];
    ushort_t* hi[5];
    int n4[5];
};

__global__ __launch_bounds__(256) void cast_all_kernel(CastJobs jobs) {
    int j = blockIdx.y;
    int i = blockIdx.x * 256 + threadIdx.x;
    if (i >= jobs.n4[j]) return;
    float4 f = ((const float4*)jobs.in[j])[i];
    uint2 h;
    h.x = pk_bf16(f.x, f.y);
    h.y = pk_bf16(f.z, f.w);
    ((uint2*)jobs.hi[j])[i] = h;
}

// ---------------- async global -> LDS (16B per lane) ----------------
__device__ __forceinline__ void async16(const ushort_t* g, ushort_t* l) {
    __builtin_amdgcn_global_load_lds(
        (const __attribute__((address_space(1))) void*)g,
        (__attribute__((address_space(3))) void*)l, 16, 0, 0);
}

// ============== single-bf16 MFMA GEMM (LDS-staged) ==============
// R10 lesson: fragment-direct global loads are UNcoalesced -> keep LDS staging.

// --- QKV variant, 128x128 tile, 4 waves (2x2 wave grid), BK=64.
// Swizzle gc = kp ^ (row & 7); fragment slot = (sub*4 + quad) ^ (row & 7)
// -> 2-way bank aliasing (free).
// q output is PRE-SCALED by SCALE*log2(e): its only consumers (QK MFMA and the
// global-key dot) want the scaled score, so attention's hot loop drops a mul.
__global__ __launch_bounds__(256) void gemm_qkv_kernel(
    const ushort_t* __restrict__ xb,
    const ushort_t* __restrict__ wqb, const float* __restrict__ bq,
    const ushort_t* __restrict__ wkb, const float* __restrict__ bk,
    const ushort_t* __restrict__ wvb, const float* __restrict__ bv,
    ushort_t* __restrict__ qb, ushort_t* __restrict__ kb,
    ushort_t* __restrict__ vtb)
{
    __shared__ ushort_t sA[128 * 64];   // 16 KB
    __shared__ ushort_t sB[128 * 64];   // 16 KB
    const int tid  = threadIdx.x;
    const int lane = tid & 63;
    const int w    = tid >> 6;          // 0..3
    const int wr   = w >> 1, wc = w & 1;
    const int quad = lane >> 4, lm = lane & 15;
    const int seg  = blockIdx.x >> 3;
    const int bn   = (blockIdx.x & 7) * 128;
    const int bm   = blockIdx.y * 128;

    const ushort_t* B  = (seg == 0) ? wqb : (seg == 1) ? wkb : wvb;
    const float* bias  = (seg == 0) ? bq  : (seg == 1) ? bk  : bv;

    f32x4 acc[4][4];
#pragma unroll
    for (int i = 0; i < 4; ++i)
#pragma unroll
        for (int j = 0; j < 4; ++j) acc[i][j] = {0.f, 0.f, 0.f, 0.f};

    for (int k0 = 0; k0 < HID; k0 += 64) {
        __syncthreads();
#pragma unroll
        for (int t = 0; t < 4; ++t) {          // A,B: 1024 chunks each, 4/thread
            int c = tid + t * 256;
            int row = c >> 3, kp = c & 7, gc = kp ^ (row & 7);
            async16(&xb[(size_t)(bm + row) * HID + k0 + gc * 8], &sA[c * 8]);
            async16(&B[(size_t)(bn + row) * HID + k0 + gc * 8], &sB[c * 8]);
        }
        asm volatile("s_waitcnt vmcnt(0)" ::: "memory");
        __syncthreads();

        // two BK=32 sub-steps per staged tile
#pragma unroll
        for (int sub = 0; sub < 2; ++sub) {
            bf16x8 af[4], bf[4];
#pragma unroll
            for (int i = 0; i < 4; ++i) {
                int row = wr * 64 + i * 16 + lm;
                int slot = (sub * 4 + quad) ^ (row & 7);
                af[i] = *(const bf16x8*)&sA[row * 64 + slot * 8];
            }
#pragma unroll
            for (int j = 0; j < 4; ++j) {
                int row = wc * 64 + j * 16 + lm;
                int slot = (sub * 4 + quad) ^ (row & 7);
                bf[j] = *(const bf16x8*)&sB[row * 64 + slot * 8];
            }
#pragma unroll
            for (int i = 0; i < 4; ++i)
#pragma unroll
                for (int j = 0; j < 4; ++j)
                    acc[i][j] = __builtin_amdgcn_mfma_f32_16x16x32_bf16(af[i], bf[j], acc[i][j], 0, 0, 0);
        }
    }

    // epilogue: C/D layout col=lane&15, row=quad*4+reg
    const float qsc = (seg == 0) ? SCALE_LOG2E : 1.0f;
#pragma unroll
    for (int i = 0; i < 4; ++i)
#pragma unroll
        for (int j = 0; j < 4; ++j) {
            int col = bn + wc * 64 + j * 16 + lm;
            float b = bias[col];
            int row0 = bm + wr * 64 + i * 16 + quad * 4;
            if (seg == 2) {
                // transposed V: r=0..3 are consecutive jj -> one 8B store
                int hh = col >> 6, dd = col & 63, nn = row0 >> 9, jj = row0 & 511;
                uint2 v4;
                v4.x = pk_bf16(acc[i][j][0] + b, acc[i][j][1] + b);
                v4.y = pk_bf16(acc[i][j][2] + b, acc[i][j][3] + b);
                *(uint2*)&vtb[(((size_t)nn * NH + hh) * HD + dd) * WIN + jj] = v4;
            } else {
                ushort_t* dst = (seg == 0) ? qb : kb;
                unsigned int c01 = pk_bf16((acc[i][j][0] + b) * qsc, (acc[i][j][1] + b) * qsc);
                unsigned int c23 = pk_bf16((acc[i][j][2] + b) * qsc, (acc[i][j][3] + b) * qsc);
                dst[(size_t)(row0 + 0) * HID + col] = (ushort_t)(c01 & 0xFFFFu);
                dst[(size_t)(row0 + 1) * HID + col] = (ushort_t)(c01 >> 16);
                dst[(size_t)(row0 + 2) * HID + col] = (ushort_t)(c23 & 0xFFFFu);
                dst[(size_t)(row0 + 3) * HID + col] = (ushort_t)(c23 >> 16);
            }
        }
}

// --- out-proj: 64x64 x K=1024, BK=64, fused bias, fp32 out ---
__global__ __launch_bounds__(128) void gemm_out_kernel(
    const ushort_t* __restrict__ A, const ushort_t* __restrict__ B,
    const float* __restrict__ bias, float* __restrict__ out)
{
    __shared__ ushort_t sA[64 * 64];   // 8 KB
    __shared__ ushort_t sB[64 * 64];   // 8 KB
    const int tid  = threadIdx.x;
    const int lane = tid & 63;
    const int w    = tid >> 6;
    const int quad = lane >> 4, lm = lane & 15;
    const int bn   = blockIdx.x * 64;
    const int bm   = blockIdx.y * 64;

    f32x4 acc[2][4];   // wave tile 32x64
#pragma unroll
    for (int i = 0; i < 2; ++i)
#pragma unroll
        for (int j = 0; j < 4; ++j) acc[i][j] = {0.f, 0.f, 0.f, 0.f};

    for (int k0 = 0; k0 < HID; k0 += 64) {
        __syncthreads();
#pragma unroll
        for (int t = 0; t < 4; ++t) {          // A,B: 512 chunks each, 4/thread
            int c = tid + t * 128;
            int row = c >> 3, kp = c & 7, gc = kp ^ (row & 7);
            async16(&A[(size_t)(bm + row) * HID + k0 + gc * 8], &sA[c * 8]);
            async16(&B[(size_t)(bn + row) * HID + k0 + gc * 8], &sB[c * 8]);
        }
        asm volatile("s_waitcnt vmcnt(0)" ::: "memory");
        __syncthreads();

#pragma unroll
        for (int sub = 0; sub < 2; ++sub) {
            bf16x8 af[2], bf[4];
#pragma unroll
            for (int i = 0; i < 2; ++i) {
                int row = w * 32 + i * 16 + lm;
                int slot = (sub * 4 + quad) ^ (row & 7);
                af[i] = *(const bf16x8*)&sA[row * 64 + slot * 8];
            }
#pragma unroll
            for (int j = 0; j < 4; ++j) {
                int row = j * 16 + lm;
                int slot = (sub * 4 + quad) ^ (row & 7);
                bf[j] = *(const bf16x8*)&sB[row * 64 + slot * 8];
            }
#pragma unroll
            for (int i = 0; i < 2; ++i)
#pragma unroll
                for (int j = 0; j < 4; ++j)
                    acc[i][j] = __builtin_amdgcn_mfma_f32_16x16x32_bf16(af[i], bf[j], acc[i][j], 0, 0, 0);
        }
    }

#pragma unroll
    for (int i = 0; i < 2; ++i)
#pragma unroll
        for (int j = 0; j < 4; ++j) {
            int col = bn + j * 16 + lm;
            float b = bias[col];
#pragma unroll
            for (int r = 0; r < 4; ++r) {
                int row = bm + w * 32 + i * 16 + quad * 4 + r;
                out[(size_t)row * HID + col] = acc[i][j][r] + b;
            }
        }
}

// ---------------- V sums from transposed bf16 V: wave per (n,h,d) row ----------------
__global__ __launch_bounds__(256) void vsum_kernel(const ushort_t* __restrict__ vtb,
    float* __restrict__ vwin, float* __restrict__ vgwin)
{
    int wid  = blockIdx.x * 4 + (threadIdx.x >> 6);   // 0..4095 = (n*NH+h)*HD+d
    int lane = threadIdx.x & 63;
    bf16x8 v = *(const bf16x8*)&vtb[(size_t)wid * WIN + lane * 8];
    float s = 0.f;
#pragma unroll
    for (int e = 0; e < 8; ++e) s += (float)v[e];
    float sg = ((lane & 3) == 0) ? (float)v[0] : 0.f;  // j = lane*8, j%32==0 iff lane%4==0
#pragma unroll
    for (int off = 1; off < 64; off <<= 1) {
        s  += __shfl_xor(s,  off);
        sg += __shfl_xor(sg, off);
    }
    if (lane == 0) { vwin[wid] = s; vgwin[wid] = sg; }
}

// ---------------- MFMA flash attention: S^T formulation, 64-query tiles ----------------
// Grid (8 qtiles of 64, 16 heads, 4 windows) = 512 blocks, 256 thr = 4 waves.
// MEASURED (round-3 probe): ~26.5 us per launch incl. dispatch boundary.
__global__ __launch_bounds__(256) void attn_mfma_kernel(
    const ushort_t* __restrict__ qb, const ushort_t* __restrict__ kb,
    const ushort_t* __restrict__ vtb,
    const float* __restrict__ vwin, const float* __restrict__ vgwin,
    ushort_t* __restrict__ ath)
{
    __shared__ __align__(16) ushort_t sK[64 * 64];    // [key][8 chunks of 8 d], swizzled
    __shared__ __align__(16) ushort_t sVt[64 * 64];   // [d][8 chunks of 8 j], swizzled
    __shared__ __align__(16) ushort_t sP[4][16 * 68]; // per-wave P[q][key], 68-padded rows
    __shared__ float sPe[96];                          // 2 global queries x 48 keys
    __shared__ float sAe[2][64];
    __shared__ float sLe0[2];

    const int tid  = threadIdx.x;
    const int lane = tid & 63;
    const int w    = tid >> 6;     // 0..3
    const int quad = lane >> 4;
    const int lm   = lane & 15;
    const int tile = blockIdx.x;   // 0..7
    const int h    = blockIdx.y;
    const int n    = blockIdx.z;

    const ushort_t* kbase = &kb[(size_t)(n * WIN) * HID + h * HD];
    const ushort_t* vbase = &vtb[(size_t)(n * NH + h) * HD * WIN];

    const size_t qrow = (size_t)(n * WIN + tile * 64 + w * 16 + lm);
    const bf16x8 aq0 = *(const bf16x8*)&qb[qrow * HID + h * HD + quad * 8];
    const bf16x8 aq1 = *(const bf16x8*)&qb[qrow * HID + h * HD + 32 + quad * 8];

    f32x4 acc[4];
#pragma unroll
    for (int dt = 0; dt < 4; ++dt) acc[dt] = {0.f, 0.f, 0.f, 0.f};
    float lac = 0.f;                       // denominator partial for query lm
    // query global <=> (tile*64 + w*16 + lm) % 32 == 0 <=> lm==0 && w even
    const bool qgl = (lm == 0) && ((w & 1) == 0);

    ushort_t* sPw = sP[w];

    for (int c = 0; c < 8; ++c) {
        __syncthreads();
        // stage 64 keys of K first (2 instrs/thread), then 64 d-rows of Vt
#pragma unroll
        for (int t = 0; t < 2; ++t) {
            int c2 = tid + t * 256;
            int key = c2 >> 3, ck = c2 & 7, gc = ck ^ (key & 7);
            async16(&kbase[(size_t)(c * 64 + key) * HID + gc * 8], &sK[c2 * 8]);
        }
#pragma unroll
        for (int t = 0; t < 2; ++t) {
            int c2 = tid + t * 256;
            int dd = c2 >> 3, sl = c2 & 7, gj = sl ^ (dd & 7);
            async16(&vbase[(size_t)dd * WIN + c * 64 + gj * 8], &sVt[c2 * 8]);
        }
        asm volatile("s_waitcnt vmcnt(2)" ::: "memory");   // own K loads done
        __syncthreads();

        // ---- S^T = K.Q^T + softmax numerators (shift m=0 safe: |s| < ~4) ----
#pragma unroll
        for (int jt = 0; jt < 4; ++jt) {
            int key = jt * 16 + lm;
            bf16x8 ak0 = *(const bf16x8*)&sK[key * 64 + ((quad) ^ (key & 7)) * 8];
            bf16x8 ak1 = *(const bf16x8*)&sK[key * 64 + ((4 + quad) ^ (key & 7)) * 8];
            f32x4 s = {0.f, 0.f, 0.f, 0.f};
            s = __builtin_amdgcn_mfma_f32_16x16x32_bf16(ak0, aq0, s, 0, 0, 0);
            s = __builtin_amdgcn_mfma_f32_16x16x32_bf16(ak1, aq1, s, 0, 0, 0);
            // s[r]: key = jt*16 + quad*4 + r, query = lm  (already log2e-scaled)
            const bool kg = ((jt & 1) == 0) && (quad == 0);  // key%32==0 needs r==0 too
            float p[4];
#pragma unroll
            for (int r = 0; r < 4; ++r) {
                float sv = s[r];
                if (qgl && kg && r == 0) sv += sv;   // in-window global pair: 2x score
                p[r] = EXP2F(sv);
                lac += p[r];                         // unrounded denominator
            }
            uint2 pp;
            pp.x = pk_bf16(p[0], p[1]);
            pp.y = pk_bf16(p[2], p[3]);
            // P[q=lm][key=jt*16+quad*4 .. +3] -> one 8B LDS store
            *(uint2*)&sPw[lm * 68 + jt * 16 + quad * 4] = pp;
        }

        asm volatile("s_waitcnt vmcnt(0)" ::: "memory");   // all V loads done
        __syncthreads();

        // ---- PV: P (A-layout, contiguous row read) x Vt (B-layout) ----
        bf16x8 pf[2];
        pf[0] = *(const bf16x8*)&sPw[lm * 68 + quad * 8];
        pf[1] = *(const bf16x8*)&sPw[lm * 68 + 32 + quad * 8];
#pragma unroll
        for (int dt = 0; dt < 4; ++dt) {
            int d = dt * 16 + lm;
#pragma unroll
            for (int jc = 0; jc < 2; ++jc) {
                bf16x8 vf = *(const bf16x8*)&sVt[d * 64 + (((jc * 4 + quad) ^ (d & 7))) * 8];
                acc[dt] = __builtin_amdgcn_mfma_f32_16x16x32_bf16(pf[jc], vf, acc[dt], 0, 0, 0);
            }
        }
    }

    // ---- denominator: reduce over the 4 quads (each covered disjoint keys) ----
    float lred = lac;
    lred += __shfl_xor(lred, 16);
    lred += __shfl_xor(lred, 32);   // all lanes with same lm now hold l[query=lm]

    // ---- out-of-window global keys for the 2 global queries of this block ----
    __syncthreads();
    if (tid < 96) {
        int qq = tid / 48;                       // 0..1 -> query tile*64 + qq*32
        int kk = tid - qq * 48;
        int g = kk + (kk >= n * 16 ? 16 : 0);    // skip in-window globals
        const ushort_t* qr = &qb[(size_t)(n * WIN + tile * 64 + qq * 32) * HID + h * HD];
        const ushort_t* kr = &kb[(size_t)(g * GSTRIDE) * HID + h * HD];
        float dot = 0.f;
#pragma unroll
        for (int dc = 0; dc < 8; ++dc) {
            bf16x8 qv = *(const bf16x8*)&qr[dc * 8];
            bf16x8 kv = *(const bf16x8*)&kr[dc * 8];
#pragma unroll
            for (int e = 0; e < 8; ++e) dot += (float)qv[e] * (float)kv[e];
        }
        sPe[tid] = EXP2F(dot);    // q pre-scaled by SCALE*log2e
    }
    __syncthreads();
    if (tid < 128) {
        int qq = tid >> 6, d = tid & 63;
        float a = 0.f;
        for (int kk = 0; kk < 48; ++kk) {
            int g = kk + (kk >= n * 16 ? 16 : 0);
            int gwin = g >> 4, jj = (g & 15) * GSTRIDE;
            a += sPe[qq * 48 + kk] *
                 bf16_to_f32(vtb[((size_t)(gwin * NH + h) * HD + d) * WIN + jj]);
        }
        sAe[qq][d] = a;
    } else if (tid == 128 || tid == 129) {
        int qq = tid - 128;
        float s = 0.f;
        for (int kk = 0; kk < 48; ++kk) s += sPe[qq * 48 + kk];
        sLe0[qq] = s;
    }
    __syncthreads();

    // ---- vrest inline from the vwin/vgwin tables (16 KB, L1-hot) ----
    float vr_ng_r[4], vr_g_r[4];
#pragma unroll
    for (int dt = 0; dt < 4; ++dt) {
        int d = dt * 16 + lm;
        float vall = 0.f, vgall = 0.f;
#pragma unroll
        for (int n2 = 0; n2 < NW; ++n2) {
            vall  += vwin [(n2 * NH + h) * HD + d];
            vgall += vgwin[(n2 * NH + h) * HD + d];
        }
        float w_  = vwin [(n * NH + h) * HD + d];
        float gw_ = vgwin[(n * NH + h) * HD + d];
        vr_ng_r[dt] = vall - w_;
        vr_g_r[dt]  = vall - w_ - (vgall - gw_);
    }

    // ---- epilogue: fold zero-score keys, normalize, write bf16 ----
#pragma unroll
    for (int r = 0; r < 4; ++r) {
        int qo = w * 16 + quad * 4 + r;
        int qwin = tile * 64 + qo;
        bool isg = ((qwin & (GSTRIDE - 1)) == 0);
        int gq = (qwin >> 5) & 1;                  // which of the block's 2 globals
        float lr = __shfl(lred, quad * 4 + r);     // l for this output row's query
        float l = lr + (float)(S_LEN - WIN);       // exp(0)=1 per non-attended key
        if (isg) l += sLe0[gq] - 48.0f;            // 48 attended keys replace zeros
        float invl = 1.f / l;
        size_t row = (size_t)(n * WIN + qwin) * HID + h * HD;
#pragma unroll
        for (int dt = 0; dt < 4; ++dt) {
            int d = dt * 16 + lm;
            float o = acc[dt][r] + (isg ? (vr_g_r[dt] + sAe[gq][d]) : vr_ng_r[dt]);
            ath[row + d] = f32_to_bf16_rne(o * invl);
        }
    }
}

extern "C" void kernel_launch(void* const* d_in, const int* in_sizes, int n_in,
                              void* d_out, int out_size, void* d_ws, size_t ws_size,
                              hipStream_t stream) {
    const float* x   = (const float*)d_in[0];
    const float* wq  = (const float*)d_in[1];
    const float* bq  = (const float*)d_in[2];
    const float* wk  = (const float*)d_in[3];
    const float* bk_ = (const float*)d_in[4];
    const float* wv  = (const float*)d_in[5];
    const float* bv  = (const float*)d_in[6];
    const float* wo  = (const float*)d_in[7];
    const float* bo  = (const float*)d_in[8];
    float* out = (float*)d_out;

    const size_t M2 = 2u * 1024 * 1024, M1 = 1024 * 1024;
    float* ws = (float*)d_ws;
    float* vwin  = ws;                       // 4096 floats
    float* vgwin = vwin + NW * NH * HD;      // 4096 floats
    ushort_t* us = (ushort_t*)(ws + 16384);
    ushort_t* xb  = us;            // 4 MB
    ushort_t* wqb = xb + M2;       ushort_t* wkb = wqb + M1;
    ushort_t* wvb = wkb + M1;      ushort_t* wob = wvb + M1;
    ushort_t* qb  = wob + M1;      // 4 MB
    ushort_t* kb  = qb + M2;       // 4 MB
    ushort_t* vtb = kb + M2;       // 4 MB
    ushort_t* ath = vtb + M2;      // 4 MB

    CastJobs jobs;
    jobs.in[0] = x;  jobs.hi[0] = xb;  jobs.n4[0] = (int)(M2 / 4);
    jobs.in[1] = wq; jobs.hi[1] = wqb; jobs.n4[1] = (int)(M1 / 4);
    jobs.in[2] = wk; jobs.hi[2] = wkb; jobs.n4[2] = (int)(M1 / 4);
    jobs.in[3] = wv; jobs.hi[3] = wvb; jobs.n4[3] = (int)(M1 / 4);
    jobs.in[4] = wo; jobs.hi[4] = wob; jobs.n4[4] = (int)(M1 / 4);
    cast_all_kernel<<<dim3(2048, 5), 256, 0, stream>>>(jobs);

    // ===== ROUND-3 PROBE: gemm_qkv x5 + gemm_out x5 (both idempotent; output
    // bit-identical). attn back to 1x (measured 26.5us in round-3 probe).
    // (qkv + out + 2*boundary) ~= (dur_us - 151) / 4. Remove next round. =====
    for (int rep = 0; rep < 5; ++rep) {
        gemm_qkv_kernel<<<dim3(24, 16), 256, 0, stream>>>(
            xb, wqb, bq, wkb, bk_, wvb, bv, qb, kb, vtb);
    }

    // V sums from vtb: 4096 waves, one per (n,h,d) row
    vsum_kernel<<<1024, 256, 0, stream>>>(vtb, vwin, vgwin);

    // attention: 512 blocks (2/CU), 256 threads (4 waves), 64-query tiles
    attn_mfma_kernel<<<dim3(8, NH, NW), 256, 0, stream>>>(
        qb, kb, vtb, vwin, vgwin, ath);

    // out projection: 64x64 x K=1024, BK=64 + fused bias, 512 blocks (2/CU)
    for (int rep = 0; rep < 5; ++rep) {
        gemm_out_kernel<<<dim3(16, 32), 128, 0, stream>>>(ath, wob, bo, out);
    }
}

// Round 5
// 148.572 us; speedup vs baseline: 1.9646x; 1.9646x over previous
//
#include <hip/hip_runtime.h>
#include <hip/hip_bf16.h>

#define S_LEN   2048
#define HID     1024
#define NH      16
#define HD      64
#define WIN     512
#define NW      4
#define NG      64
#define GSTRIDE 32
#define SCALE   0.125f               // 64^-0.5
#define SCALE_LOG2E 0.180336880f    // 0.125 * log2(e)

#if __has_builtin(__builtin_amdgcn_exp2f)
#define EXP2F(x) __builtin_amdgcn_exp2f(x)
#else
#define EXP2F(x) __expf((x) * 0.6931471805599453f)
#endif

typedef __bf16 bf16x2 __attribute__((ext_vector_type(2)));
typedef __bf16 bf16x8 __attribute__((ext_vector_type(8)));
typedef float  f32x4  __attribute__((ext_vector_type(4)));
typedef unsigned short ushort_t;

// ---------------- fp32 -> bf16 helpers ----------------
__device__ __forceinline__ ushort_t f32_to_bf16_rne(float f) {
    unsigned int u = __float_as_uint(f);
    u = u + 0x7FFFu + ((u >> 16) & 1u);
    return (ushort_t)(u >> 16);
}
__device__ __forceinline__ float bf16_to_f32(ushort_t h) {
    return __uint_as_float(((unsigned int)h) << 16);
}
// packed conversion: gfx950 HW v_cvt_pk_bf16_f32 (RNE), 2 values/instruction
#if __has_builtin(__builtin_amdgcn_cvt_pk_bf16_f32)
__device__ __forceinline__ unsigned int pk_bf16(float a, float b) {
    bf16x2 t = __builtin_amdgcn_cvt_pk_bf16_f32(a, b);
    return __builtin_bit_cast(unsigned int, t);
}
#else
__device__ __forceinline__ unsigned int pk_bf16(float a, float b) {
    return (unsigned int)f32_to_bf16_rne(a) | ((unsigned int)f32_to_bf16_rne(b) << 16);
}
#endif

// ---------------- batched cast: 5 tensors fp32 -> bf16 in one launch ----------------
struct CastJobs {
    const float* in[5];
    ushort_t* hi[5];
    int n4[5];
};

__global__ __launch_bounds__(256) void cast_all_kernel(CastJobs jobs) {
    int j = blockIdx.y;
    int i = blockIdx.x * 256 + threadIdx.x;
    if (i >= jobs.n4[j]) return;
    float4 f = ((const float4*)jobs.in[j])[i];
    uint2 h;
    h.x = pk_bf16(f.x, f.y);
    h.y = pk_bf16(f.z, f.w);
    ((uint2*)jobs.hi[j])[i] = h;
}

// ---------------- async global -> LDS (16B per lane) ----------------
__device__ __forceinline__ void async16(const ushort_t* g, ushort_t* l) {
    __builtin_amdgcn_global_load_lds(
        (const __attribute__((address_space(1))) void*)g,
        (__attribute__((address_space(3))) void*)l, 16, 0, 0);
}

// ============== single-bf16 MFMA GEMM (LDS-staged) ==============
// R10 lesson: fragment-direct global loads are UNcoalesced -> keep LDS staging.

// --- QKV variant, 128x128 tile, 4 waves (2x2 wave grid), BK=64.
// MEASURED (round-4 probe): qkv + out + 2 boundaries ~= 35 us.
__global__ __launch_bounds__(256) void gemm_qkv_kernel(
    const ushort_t* __restrict__ xb,
    const ushort_t* __restrict__ wqb, const float* __restrict__ bq,
    const ushort_t* __restrict__ wkb, const float* __restrict__ bk,
    const ushort_t* __restrict__ wvb, const float* __restrict__ bv,
    ushort_t* __restrict__ qb, ushort_t* __restrict__ kb,
    ushort_t* __restrict__ vtb)
{
    __shared__ ushort_t sA[128 * 64];   // 16 KB
    __shared__ ushort_t sB[128 * 64];   // 16 KB
    const int tid  = threadIdx.x;
    const int lane = tid & 63;
    const int w    = tid >> 6;          // 0..3
    const int wr   = w >> 1, wc = w & 1;
    const int quad = lane >> 4, lm = lane & 15;
    const int seg  = blockIdx.x >> 3;
    const int bn   = (blockIdx.x & 7) * 128;
    const int bm   = blockIdx.y * 128;

    const ushort_t* B  = (seg == 0) ? wqb : (seg == 1) ? wkb : wvb;
    const float* bias  = (seg == 0) ? bq  : (seg == 1) ? bk  : bv;

    f32x4 acc[4][4];
#pragma unroll
    for (int i = 0; i < 4; ++i)
#pragma unroll
        for (int j = 0; j < 4; ++j) acc[i][j] = {0.f, 0.f, 0.f, 0.f};

    for (int k0 = 0; k0 < HID; k0 += 64) {
        __syncthreads();
#pragma unroll
        for (int t = 0; t < 4; ++t) {          // A,B: 1024 chunks each, 4/thread
            int c = tid + t * 256;
            int row = c >> 3, kp = c & 7, gc = kp ^ (row & 7);
            async16(&xb[(size_t)(bm + row) * HID + k0 + gc * 8], &sA[c * 8]);
            async16(&B[(size_t)(bn + row) * HID + k0 + gc * 8], &sB[c * 8]);
        }
        asm volatile("s_waitcnt vmcnt(0)" ::: "memory");
        __syncthreads();

        // two BK=32 sub-steps per staged tile
#pragma unroll
        for (int sub = 0; sub < 2; ++sub) {
            bf16x8 af[4], bf[4];
#pragma unroll
            for (int i = 0; i < 4; ++i) {
                int row = wr * 64 + i * 16 + lm;
                int slot = (sub * 4 + quad) ^ (row & 7);
                af[i] = *(const bf16x8*)&sA[row * 64 + slot * 8];
            }
#pragma unroll
            for (int j = 0; j < 4; ++j) {
                int row = wc * 64 + j * 16 + lm;
                int slot = (sub * 4 + quad) ^ (row & 7);
                bf[j] = *(const bf16x8*)&sB[row * 64 + slot * 8];
            }
#pragma unroll
            for (int i = 0; i < 4; ++i)
#pragma unroll
                for (int j = 0; j < 4; ++j)
                    acc[i][j] = __builtin_amdgcn_mfma_f32_16x16x32_bf16(af[i], bf[j], acc[i][j], 0, 0, 0);
        }
    }

    // epilogue: C/D layout col=lane&15, row=quad*4+reg
    const float qsc = (seg == 0) ? SCALE_LOG2E : 1.0f;
#pragma unroll
    for (int i = 0; i < 4; ++i)
#pragma unroll
        for (int j = 0; j < 4; ++j) {
            int col = bn + wc * 64 + j * 16 + lm;
            float b = bias[col];
            int row0 = bm + wr * 64 + i * 16 + quad * 4;
            if (seg == 2) {
                // transposed V: r=0..3 are consecutive jj -> one 8B store
                int hh = col >> 6, dd = col & 63, nn = row0 >> 9, jj = row0 & 511;
                uint2 v4;
                v4.x = pk_bf16(acc[i][j][0] + b, acc[i][j][1] + b);
                v4.y = pk_bf16(acc[i][j][2] + b, acc[i][j][3] + b);
                *(uint2*)&vtb[(((size_t)nn * NH + hh) * HD + dd) * WIN + jj] = v4;
            } else {
                ushort_t* dst = (seg == 0) ? qb : kb;
                unsigned int c01 = pk_bf16((acc[i][j][0] + b) * qsc, (acc[i][j][1] + b) * qsc);
                unsigned int c23 = pk_bf16((acc[i][j][2] + b) * qsc, (acc[i][j][3] + b) * qsc);
                dst[(size_t)(row0 + 0) * HID + col] = (ushort_t)(c01 & 0xFFFFu);
                dst[(size_t)(row0 + 1) * HID + col] = (ushort_t)(c01 >> 16);
                dst[(size_t)(row0 + 2) * HID + col] = (ushort_t)(c23 & 0xFFFFu);
                dst[(size_t)(row0 + 3) * HID + col] = (ushort_t)(c23 >> 16);
            }
        }
}

// --- out-proj: 64x64 x K=1024, BK=64, fused bias, fp32 out ---
__global__ __launch_bounds__(128) void gemm_out_kernel(
    const ushort_t* __restrict__ A, const ushort_t* __restrict__ B,
    const float* __restrict__ bias, float* __restrict__ out)
{
    __shared__ ushort_t sA[64 * 64];   // 8 KB
    __shared__ ushort_t sB[64 * 64];   // 8 KB
    const int tid  = threadIdx.x;
    const int lane = tid & 63;
    const int w    = tid >> 6;
    const int quad = lane >> 4, lm = lane & 15;
    const int bn   = blockIdx.x * 64;
    const int bm   = blockIdx.y * 64;

    f32x4 acc[2][4];   // wave tile 32x64
#pragma unroll
    for (int i = 0; i < 2; ++i)
#pragma unroll
        for (int j = 0; j < 4; ++j) acc[i][j] = {0.f, 0.f, 0.f, 0.f};

    for (int k0 = 0; k0 < HID; k0 += 64) {
        __syncthreads();
#pragma unroll
        for (int t = 0; t < 4; ++t) {          // A,B: 512 chunks each, 4/thread
            int c = tid + t * 128;
            int row = c >> 3, kp = c & 7, gc = kp ^ (row & 7);
            async16(&A[(size_t)(bm + row) * HID + k0 + gc * 8], &sA[c * 8]);
            async16(&B[(size_t)(bn + row) * HID + k0 + gc * 8], &sB[c * 8]);
        }
        asm volatile("s_waitcnt vmcnt(0)" ::: "memory");
        __syncthreads();

#pragma unroll
        for (int sub = 0; sub < 2; ++sub) {
            bf16x8 af[2], bf[4];
#pragma unroll
            for (int i = 0; i < 2; ++i) {
                int row = w * 32 + i * 16 + lm;
                int slot = (sub * 4 + quad) ^ (row & 7);
                af[i] = *(const bf16x8*)&sA[row * 64 + slot * 8];
            }
#pragma unroll
            for (int j = 0; j < 4; ++j) {
                int row = j * 16 + lm;
                int slot = (sub * 4 + quad) ^ (row & 7);
                bf[j] = *(const bf16x8*)&sB[row * 64 + slot * 8];
            }
#pragma unroll
            for (int i = 0; i < 2; ++i)
#pragma unroll
                for (int j = 0; j < 4; ++j)
                    acc[i][j] = __builtin_amdgcn_mfma_f32_16x16x32_bf16(af[i], bf[j], acc[i][j], 0, 0, 0);
        }
    }

#pragma unroll
    for (int i = 0; i < 2; ++i)
#pragma unroll
        for (int j = 0; j < 4; ++j) {
            int col = bn + j * 16 + lm;
            float b = bias[col];
#pragma unroll
            for (int r = 0; r < 4; ++r) {
                int row = bm + w * 32 + i * 16 + quad * 4 + r;
                out[(size_t)row * HID + col] = acc[i][j][r] + b;
            }
        }
}

// ---------------- V sums from transposed bf16 V: wave per (n,h,d) row ----------------
__global__ __launch_bounds__(256) void vsum_kernel(const ushort_t* __restrict__ vtb,
    float* __restrict__ vwin, float* __restrict__ vgwin)
{
    int wid  = blockIdx.x * 4 + (threadIdx.x >> 6);   // 0..4095 = (n*NH+h)*HD+d
    int lane = threadIdx.x & 63;
    bf16x8 v = *(const bf16x8*)&vtb[(size_t)wid * WIN + lane * 8];
    float s = 0.f;
#pragma unroll
    for (int e = 0; e < 8; ++e) s += (float)v[e];
    float sg = ((lane & 3) == 0) ? (float)v[0] : 0.f;  // j = lane*8, j%32==0 iff lane%4==0
#pragma unroll
    for (int off = 1; off < 64; off <<= 1) {
        s  += __shfl_xor(s,  off);
        sg += __shfl_xor(sg, off);
    }
    if (lane == 0) { vwin[wid] = s; vgwin[wid] = sg; }
}

// ---------------- MFMA flash attention: S^T formulation, 64-query tiles ----------------
// Grid (8 qtiles of 64, 16 heads, 4 windows) = 512 blocks, 256 thr = 4 waves.
// MEASURED (round-3 probe): ~26.5 us/launch with the serial 2-phase stage.
// ROUND-4 CHANGE (T3 minimum-2-phase): K/Vt double-buffered in LDS. Tile c+1's
// global_load_lds are issued BEFORE computing tile c; the wait is vmcnt(4)
// (only the 4 newest instrs -- tile c+1 -- may remain in flight), so tile c's
// loads have a full iteration of compute to land. Exposed L2 latency -> ~0.
// Same data, same compute order -> bit-identical output.
__global__ __launch_bounds__(256) void attn_mfma_kernel(
    const ushort_t* __restrict__ qb, const ushort_t* __restrict__ kb,
    const ushort_t* __restrict__ vtb,
    const float* __restrict__ vwin, const float* __restrict__ vgwin,
    ushort_t* __restrict__ ath)
{
    __shared__ __align__(16) ushort_t sK[2][64 * 64];   // 2 x 8 KB, swizzled
    __shared__ __align__(16) ushort_t sVt[2][64 * 64];  // 2 x 8 KB, swizzled
    __shared__ __align__(16) ushort_t sP[4][16 * 68];   // per-wave P[q][key], 68-padded
    __shared__ float sPe[96];                            // 2 global queries x 48 keys
    __shared__ float sAe[2][64];
    __shared__ float sLe0[2];

    const int tid  = threadIdx.x;
    const int lane = tid & 63;
    const int w    = tid >> 6;     // 0..3
    const int quad = lane >> 4;
    const int lm   = lane & 15;
    const int tile = blockIdx.x;   // 0..7
    const int h    = blockIdx.y;
    const int n    = blockIdx.z;

    const ushort_t* kbase = &kb[(size_t)(n * WIN) * HID + h * HD];
    const ushort_t* vbase = &vtb[(size_t)(n * NH + h) * HD * WIN];

    const size_t qrow = (size_t)(n * WIN + tile * 64 + w * 16 + lm);
    const bf16x8 aq0 = *(const bf16x8*)&qb[qrow * HID + h * HD + quad * 8];
    const bf16x8 aq1 = *(const bf16x8*)&qb[qrow * HID + h * HD + 32 + quad * 8];

    // stage tile cc of K/Vt into buffer bb (4 global_load_lds instrs per wave)
    auto stage_kv = [&](int cc, int bb) {
#pragma unroll
        for (int t = 0; t < 2; ++t) {
            int c2 = tid + t * 256;
            int key = c2 >> 3, ck = c2 & 7, gc = ck ^ (key & 7);
            async16(&kbase[(size_t)(cc * 64 + key) * HID + gc * 8], &sK[bb][c2 * 8]);
        }
#pragma unroll
        for (int t = 0; t < 2; ++t) {
            int c2 = tid + t * 256;
            int dd = c2 >> 3, sl = c2 & 7, gj = sl ^ (dd & 7);
            async16(&vbase[(size_t)dd * WIN + cc * 64 + gj * 8], &sVt[bb][c2 * 8]);
        }
    };

    f32x4 acc[4];
#pragma unroll
    for (int dt = 0; dt < 4; ++dt) acc[dt] = {0.f, 0.f, 0.f, 0.f};
    float lac = 0.f;                       // denominator partial for query lm
    // query global <=> (tile*64 + w*16 + lm) % 32 == 0 <=> lm==0 && w even
    const bool qgl = (lm == 0) && ((w & 1) == 0);

    ushort_t* sPw = sP[w];

    stage_kv(0, 0);                        // prologue: tile 0 in flight

    for (int c = 0; c < 8; ++c) {
        const int cur = c & 1;
        if (c < 7) {
            // issue next tile first; buf[cur^1] was last read in iter c-1 and
            // is protected by that iteration's trailing barrier.
            stage_kv(c + 1, cur ^ 1);
            asm volatile("s_waitcnt vmcnt(4)" ::: "memory");   // tile c landed
        } else {
            asm volatile("s_waitcnt vmcnt(0)" ::: "memory");   // last tile
        }
        __syncthreads();   // all waves' tile-c loads visible

        // ---- S^T = K.Q^T + softmax numerators (shift m=0 safe: |s| < ~4) ----
#pragma unroll
        for (int jt = 0; jt < 4; ++jt) {
            int key = jt * 16 + lm;
            bf16x8 ak0 = *(const bf16x8*)&sK[cur][key * 64 + ((quad) ^ (key & 7)) * 8];
            bf16x8 ak1 = *(const bf16x8*)&sK[cur][key * 64 + ((4 + quad) ^ (key & 7)) * 8];
            f32x4 s = {0.f, 0.f, 0.f, 0.f};
            s = __builtin_amdgcn_mfma_f32_16x16x32_bf16(ak0, aq0, s, 0, 0, 0);
            s = __builtin_amdgcn_mfma_f32_16x16x32_bf16(ak1, aq1, s, 0, 0, 0);
            // s[r]: key = jt*16 + quad*4 + r, query = lm  (already log2e-scaled)
            const bool kg = ((jt & 1) == 0) && (quad == 0);  // key%32==0 needs r==0 too
            float p[4];
#pragma unroll
            for (int r = 0; r < 4; ++r) {
                float sv = s[r];
                if (qgl && kg && r == 0) sv += sv;   // in-window global pair: 2x score
                p[r] = EXP2F(sv);
                lac += p[r];                         // unrounded denominator
            }
            uint2 pp;
            pp.x = pk_bf16(p[0], p[1]);
            pp.y = pk_bf16(p[2], p[3]);
            // P[q=lm][key=jt*16+quad*4 .. +3] -> one 8B LDS store
            *(uint2*)&sPw[lm * 68 + jt * 16 + quad * 4] = pp;
        }

        // ---- PV: P (A-layout, contiguous row read) x Vt (B-layout) ----
        bf16x8 pf[2];
        pf[0] = *(const bf16x8*)&sPw[lm * 68 + quad * 8];
        pf[1] = *(const bf16x8*)&sPw[lm * 68 + 32 + quad * 8];
#pragma unroll
        for (int dt = 0; dt < 4; ++dt) {
            int d = dt * 16 + lm;
#pragma unroll
            for (int jc = 0; jc < 2; ++jc) {
                bf16x8 vf = *(const bf16x8*)&sVt[cur][d * 64 + (((jc * 4 + quad) ^ (d & 7))) * 8];
                acc[dt] = __builtin_amdgcn_mfma_f32_16x16x32_bf16(pf[jc], vf, acc[dt], 0, 0, 0);
            }
        }

        __syncthreads();   // all reads of buf[cur] done before c+1 overwrites it
    }

    // ---- denominator: reduce over the 4 quads (each covered disjoint keys) ----
    float lred = lac;
    lred += __shfl_xor(lred, 16);
    lred += __shfl_xor(lred, 32);   // all lanes with same lm now hold l[query=lm]

    // ---- out-of-window global keys for the 2 global queries of this block ----
    __syncthreads();
    if (tid < 96) {
        int qq = tid / 48;                       // 0..1 -> query tile*64 + qq*32
        int kk = tid - qq * 48;
        int g = kk + (kk >= n * 16 ? 16 : 0);    // skip in-window globals
        const ushort_t* qr = &qb[(size_t)(n * WIN + tile * 64 + qq * 32) * HID + h * HD];
        const ushort_t* kr = &kb[(size_t)(g * GSTRIDE) * HID + h * HD];
        float dot = 0.f;
#pragma unroll
        for (int dc = 0; dc < 8; ++dc) {
            bf16x8 qv = *(const bf16x8*)&qr[dc * 8];
            bf16x8 kv = *(const bf16x8*)&kr[dc * 8];
#pragma unroll
            for (int e = 0; e < 8; ++e) dot += (float)qv[e] * (float)kv[e];
        }
        sPe[tid] = EXP2F(dot);    // q pre-scaled by SCALE*log2e
    }
    __syncthreads();
    if (tid < 128) {
        int qq = tid >> 6, d = tid & 63;
        float a = 0.f;
        for (int kk = 0; kk < 48; ++kk) {
            int g = kk + (kk >= n * 16 ? 16 : 0);
            int gwin = g >> 4, jj = (g & 15) * GSTRIDE;
            a += sPe[qq * 48 + kk] *
                 bf16_to_f32(vtb[((size_t)(gwin * NH + h) * HD + d) * WIN + jj]);
        }
        sAe[qq][d] = a;
    } else if (tid == 128 || tid == 129) {
        int qq = tid - 128;
        float s = 0.f;
        for (int kk = 0; kk < 48; ++kk) s += sPe[qq * 48 + kk];
        sLe0[qq] = s;
    }
    __syncthreads();

    // ---- vrest inline from the vwin/vgwin tables (16 KB, L1-hot) ----
    float vr_ng_r[4], vr_g_r[4];
#pragma unroll
    for (int dt = 0; dt < 4; ++dt) {
        int d = dt * 16 + lm;
        float vall = 0.f, vgall = 0.f;
#pragma unroll
        for (int n2 = 0; n2 < NW; ++n2) {
            vall  += vwin [(n2 * NH + h) * HD + d];
            vgall += vgwin[(n2 * NH + h) * HD + d];
        }
        float w_  = vwin [(n * NH + h) * HD + d];
        float gw_ = vgwin[(n * NH + h) * HD + d];
        vr_ng_r[dt] = vall - w_;
        vr_g_r[dt]  = vall - w_ - (vgall - gw_);
    }

    // ---- epilogue: fold zero-score keys, normalize, write bf16 ----
#pragma unroll
    for (int r = 0; r < 4; ++r) {
        int qo = w * 16 + quad * 4 + r;
        int qwin = tile * 64 + qo;
        bool isg = ((qwin & (GSTRIDE - 1)) == 0);
        int gq = (qwin >> 5) & 1;                  // which of the block's 2 globals
        float lr = __shfl(lred, quad * 4 + r);     // l for this output row's query
        float l = lr + (float)(S_LEN - WIN);       // exp(0)=1 per non-attended key
        if (isg) l += sLe0[gq] - 48.0f;            // 48 attended keys replace zeros
        float invl = 1.f / l;
        size_t row = (size_t)(n * WIN + qwin) * HID + h * HD;
#pragma unroll
        for (int dt = 0; dt < 4; ++dt) {
            int d = dt * 16 + lm;
            float o = acc[dt][r] + (isg ? (vr_g_r[dt] + sAe[gq][d]) : vr_ng_r[dt]);
            ath[row + d] = f32_to_bf16_rne(o * invl);
        }
    }
}

extern "C" void kernel_launch(void* const* d_in, const int* in_sizes, int n_in,
                              void* d_out, int out_size, void* d_ws, size_t ws_size,
                              hipStream_t stream) {
    const float* x   = (const float*)d_in[0];
    const float* wq  = (const float*)d_in[1];
    const float* bq  = (const float*)d_in[2];
    const float* wk  = (const float*)d_in[3];
    const float* bk_ = (const float*)d_in[4];
    const float* wv  = (const float*)d_in[5];
    const float* bv  = (const float*)d_in[6];
    const float* wo  = (const float*)d_in[7];
    const float* bo  = (const float*)d_in[8];
    float* out = (float*)d_out;

    const size_t M2 = 2u * 1024 * 1024, M1 = 1024 * 1024;
    float* ws = (float*)d_ws;
    float* vwin  = ws;                       // 4096 floats
    float* vgwin = vwin + NW * NH * HD;      // 4096 floats
    ushort_t* us = (ushort_t*)(ws + 16384);
    ushort_t* xb  = us;            // 4 MB
    ushort_t* wqb = xb + M2;       ushort_t* wkb = wqb + M1;
    ushort_t* wvb = wkb + M1;      ushort_t* wob = wvb + M1;
    ushort_t* qb  = wob + M1;      // 4 MB
    ushort_t* kb  = qb + M2;       // 4 MB
    ushort_t* vtb = kb + M2;       // 4 MB
    ushort_t* ath = vtb + M2;      // 4 MB

    CastJobs jobs;
    jobs.in[0] = x;  jobs.hi[0] = xb;  jobs.n4[0] = (int)(M2 / 4);
    jobs.in[1] = wq; jobs.hi[1] = wqb; jobs.n4[1] = (int)(M1 / 4);
    jobs.in[2] = wk; jobs.hi[2] = wkb; jobs.n4[2] = (int)(M1 / 4);
    jobs.in[3] = wv; jobs.hi[3] = wvb; jobs.n4[3] = (int)(M1 / 4);
    jobs.in[4] = wo; jobs.hi[4] = wob; jobs.n4[4] = (int)(M1 / 4);
    cast_all_kernel<<<dim3(2048, 5), 256, 0, stream>>>(jobs);

    // fused QKV: 128x128 blocks, BK=64, grid (3 segs x 8 cols) x 16 rows = 384 blocks
    gemm_qkv_kernel<<<dim3(24, 16), 256, 0, stream>>>(
        xb, wqb, bq, wkb, bk_, wvb, bv, qb, kb, vtb);

    // V sums from vtb: 4096 waves, one per (n,h,d) row
    vsum_kernel<<<1024, 256, 0, stream>>>(vtb, vwin, vgwin);

    // attention: 512 blocks (2/CU), 256 threads (4 waves), double-buffered K/V
    attn_mfma_kernel<<<dim3(8, NH, NW), 256, 0, stream>>>(
        qb, kb, vtb, vwin, vgwin, ath);

    // out projection: 64x64 x K=1024, BK=64 + fused bias, 512 blocks (2/CU)
    gemm_out_kernel<<<dim3(16, 32), 128, 0, stream>>>(ath, wob, bo, out);
}